// Round 1
// baseline (523.676 us; speedup 1.0000x reference)
//
#include <hip/hip_runtime.h>
#include <hip/hip_bf16.h>
#include <stdint.h>

#define D_MODEL 1024
#define NH 16
#define HD 64
#define LSEQ 2048
#define BATCH 4
#define NROWS (BATCH * LSEQ) /* 8192 */

typedef __attribute__((ext_vector_type(8))) short s16x8;
typedef __attribute__((ext_vector_type(4))) float f32x4;
typedef __attribute__((ext_vector_type(4))) int   i32x4;

static __device__ __forceinline__ f32x4 mfma_bf16(s16x8 a, s16x8 b, f32x4 c) {
    return __builtin_amdgcn_mfma_f32_16x16x32_bf16(a, b, c, 0, 0, 0);
}

static __device__ __forceinline__ unsigned short f32_to_bf16(float f) {
    unsigned int u = __float_as_uint(f);
    u = (u + 0x7fffu + ((u >> 16) & 1u)) >> 16;
    return (unsigned short)u;
}

// ---------------- conversion kernels ----------------

__global__ void cvt_f32_bf16(const float* __restrict__ in,
                             unsigned short* __restrict__ out, int n4) {
    int i = blockIdx.x * blockDim.x + threadIdx.x;
    if (i < n4) {
        float4 v = ((const float4*)in)[i];
        ushort4 o;
        o.x = f32_to_bf16(v.x); o.y = f32_to_bf16(v.y);
        o.z = f32_to_bf16(v.z); o.w = f32_to_bf16(v.w);
        ((ushort4*)out)[i] = o;
    }
}

// in: [K][N] f32  ->  out: [N][K] bf16
__global__ __launch_bounds__(256) void transpose_cvt(
    const float* __restrict__ in, unsigned short* __restrict__ out, int K, int N) {
    __shared__ float tile[32][33];
    int n0 = blockIdx.x * 32, k0 = blockIdx.y * 32;
    int tx = threadIdx.x & 31, ty = threadIdx.x >> 5; // 32 x 8
    #pragma unroll
    for (int i = 0; i < 4; i++) {
        int k = ty + i * 8;
        tile[k][tx] = in[(size_t)(k0 + k) * N + (n0 + tx)];
    }
    __syncthreads();
    #pragma unroll
    for (int i = 0; i < 4; i++) {
        int n = ty + i * 8;
        out[(size_t)(n0 + n) * K + (k0 + tx)] = f32_to_bf16(tile[tx][n]);
    }
}

// ---------------- GEMM: C[M][N] = A[M][K] * Bt[N][K]^T + bias ----------------
// 128x128 tile, BK=32, 256 threads = 4 waves (2x2), each wave 64x64 via 4x4
// 16x16x32 bf16 MFMA fragments.

template <bool OUT_BF16>
__global__ __launch_bounds__(256) void gemm_bf16(
    const unsigned short* __restrict__ A,   // [M][K] bf16
    const unsigned short* __restrict__ Bt,  // [N][K] bf16
    const float* __restrict__ bias,         // [N] f32
    void* __restrict__ C, int M, int N, int K) {
    __shared__ unsigned short As[128][40];
    __shared__ unsigned short Bs[128][40];

    const int tid = threadIdx.x;
    const int m0 = blockIdx.y * 128;
    const int n0 = blockIdx.x * 128;
    const int lane = tid & 63, w = tid >> 6;
    const int wr = w >> 1, wc = w & 1;
    const int lq = lane & 15, lk = lane >> 4;

    f32x4 acc[4][4];
    #pragma unroll
    for (int m = 0; m < 4; m++)
        #pragma unroll
        for (int n = 0; n < 4; n++)
            #pragma unroll
            for (int r = 0; r < 4; r++) acc[m][n][r] = 0.f;

    for (int k0 = 0; k0 < K; k0 += 32) {
        #pragma unroll
        for (int i = 0; i < 2; i++) {
            int c = tid + i * 256;          // 512 chunks of 16B
            int row = c >> 2, kc = (c & 3) * 8;
            i32x4 va = *(const i32x4*)(A + (size_t)(m0 + row) * K + k0 + kc);
            *(i32x4*)(&As[row][kc]) = va;
            i32x4 vb = *(const i32x4*)(Bt + (size_t)(n0 + row) * K + k0 + kc);
            *(i32x4*)(&Bs[row][kc]) = vb;
        }
        __syncthreads();
        s16x8 af[4], bf[4];
        #pragma unroll
        for (int m = 0; m < 4; m++)
            af[m] = *(const s16x8*)(&As[wr * 64 + m * 16 + lq][lk * 8]);
        #pragma unroll
        for (int n = 0; n < 4; n++)
            bf[n] = *(const s16x8*)(&Bs[wc * 64 + n * 16 + lq][lk * 8]);
        #pragma unroll
        for (int m = 0; m < 4; m++)
            #pragma unroll
            for (int n = 0; n < 4; n++)
                acc[m][n] = mfma_bf16(af[m], bf[n], acc[m][n]);
        __syncthreads();
    }

    #pragma unroll
    for (int m = 0; m < 4; m++) {
        int row = m0 + wr * 64 + m * 16 + lk * 4;
        #pragma unroll
        for (int n = 0; n < 4; n++) {
            int col = n0 + wc * 64 + n * 16 + lq;
            float bv = bias[col];
            #pragma unroll
            for (int r = 0; r < 4; r++) {
                float v = acc[m][n][r] + bv;
                if (OUT_BF16)
                    ((unsigned short*)C)[(size_t)(row + r) * N + col] = f32_to_bf16(v);
                else
                    ((float*)C)[(size_t)(row + r) * N + col] = v;
            }
        }
    }
}

// ---------------- flash attention ----------------
// grid: (L/64, B*H); 256 threads = 4 waves; wave w owns q rows [qb0+16w, +16).
// qkv: [B*L][3072] bf16 (q at +0, k at +1024, v at +2048, head h at h*64)
// out: [B*L][1024] bf16 (attention output, pre out-proj)

__global__ __launch_bounds__(256) void attn_kernel(
    const unsigned short* __restrict__ qkv, unsigned short* __restrict__ out) {
    __shared__ unsigned short Ks[64][72];
    __shared__ unsigned short VTs[64][72];  // transposed: VTs[d][kv]
    __shared__ unsigned short Ps[4][16][72];

    const int bh = blockIdx.y;
    const int b = bh >> 4, h = bh & 15;
    const int qb0 = blockIdx.x * 64;
    const int tid = threadIdx.x, lane = tid & 63, w = tid >> 6;
    const int lq = lane & 15, lk = lane >> 4;

    const size_t base = (size_t)b * LSEQ * 3072;

    // Q fragments (2 k-steps over d=64)
    s16x8 qf[2];
    {
        int qrow = qb0 + w * 16 + lq;
        const unsigned short* qp = qkv + base + (size_t)qrow * 3072 + h * 64;
        qf[0] = *(const s16x8*)(qp + lk * 8);
        qf[1] = *(const s16x8*)(qp + 32 + lk * 8);
    }

    float m_r[4], l_r[4];
    f32x4 o[4];
    #pragma unroll
    for (int r = 0; r < 4; r++) { m_r[r] = -1e30f; l_r[r] = 0.f; }
    #pragma unroll
    for (int n = 0; n < 4; n++)
        #pragma unroll
        for (int r = 0; r < 4; r++) o[n][r] = 0.f;

    const int q_row_g = qb0 + w * 16 + lk * 4; // + r
    const int nkv = qb0 / 64 + 1;

    for (int kvb = 0; kvb < nkv; kvb++) {
        const int kv0 = kvb * 64;
        // stage K tile and V^T tile (64 kv x 64 d each)
        #pragma unroll
        for (int i = 0; i < 2; i++) {
            int c = tid + i * 256;            // 512 chunks of 8 elems
            int kv = c >> 3, d8 = (c & 7) * 8;
            const unsigned short* kp =
                qkv + base + (size_t)(kv0 + kv) * 3072 + 1024 + h * 64 + d8;
            *(i32x4*)(&Ks[kv][d8]) = *(const i32x4*)kp;
            const unsigned short* vp =
                qkv + base + (size_t)(kv0 + kv) * 3072 + 2048 + h * 64 + d8;
            i32x4 vv = *(const i32x4*)vp;
            unsigned short tmp[8];
            *(i32x4*)tmp = vv;
            #pragma unroll
            for (int j = 0; j < 8; j++) VTs[d8 + j][kv] = tmp[j];
        }
        __syncthreads();

        // S = Q K^T (per-wave 16x64 tile)
        f32x4 s[4];
        #pragma unroll
        for (int n = 0; n < 4; n++)
            #pragma unroll
            for (int r = 0; r < 4; r++) s[n][r] = 0.f;
        #pragma unroll
        for (int n = 0; n < 4; n++) {
            s16x8 kf0 = *(const s16x8*)(&Ks[n * 16 + lq][lk * 8]);
            s16x8 kf1 = *(const s16x8*)(&Ks[n * 16 + lq][32 + lk * 8]);
            s[n] = mfma_bf16(qf[0], kf0, s[n]);
            s[n] = mfma_bf16(qf[1], kf1, s[n]);
        }
        // scale + causal mask
        #pragma unroll
        for (int n = 0; n < 4; n++) {
            int kvg = kv0 + n * 16 + lq;
            #pragma unroll
            for (int r = 0; r < 4; r++) {
                float v = s[n][r] * 0.125f;
                if (kvg > q_row_g + r) v = -1e30f;
                s[n][r] = v;
            }
        }
        // online softmax per row r (row lives in 16-lane group sharing lk)
        #pragma unroll
        for (int r = 0; r < 4; r++) {
            float mx = fmaxf(fmaxf(s[0][r], s[1][r]), fmaxf(s[2][r], s[3][r]));
            mx = fmaxf(mx, __shfl_xor(mx, 1, 64));
            mx = fmaxf(mx, __shfl_xor(mx, 2, 64));
            mx = fmaxf(mx, __shfl_xor(mx, 4, 64));
            mx = fmaxf(mx, __shfl_xor(mx, 8, 64));
            float mnew = fmaxf(m_r[r], mx);
            float corr = __expf(m_r[r] - mnew);
            m_r[r] = mnew;
            float sum = 0.f;
            #pragma unroll
            for (int n = 0; n < 4; n++) {
                float p = __expf(s[n][r] - mnew);
                s[n][r] = p;
                sum += p;
            }
            sum += __shfl_xor(sum, 1, 64);
            sum += __shfl_xor(sum, 2, 64);
            sum += __shfl_xor(sum, 4, 64);
            sum += __shfl_xor(sum, 8, 64);
            l_r[r] = l_r[r] * corr + sum;
            #pragma unroll
            for (int n = 0; n < 4; n++) o[n][r] *= corr;
        }
        // write P (bf16) to wave-private LDS
        #pragma unroll
        for (int n = 0; n < 4; n++)
            #pragma unroll
            for (int r = 0; r < 4; r++)
                Ps[w][lk * 4 + r][n * 16 + lq] = f32_to_bf16(s[n][r]);
        asm volatile("s_waitcnt lgkmcnt(0)" ::: "memory");
        // O += P V
        #pragma unroll
        for (int kk = 0; kk < 2; kk++) {
            s16x8 pa = *(const s16x8*)(&Ps[w][lq][kk * 32 + lk * 8]);
            #pragma unroll
            for (int n = 0; n < 4; n++) {
                s16x8 vf = *(const s16x8*)(&VTs[n * 16 + lq][kk * 32 + lk * 8]);
                o[n] = mfma_bf16(pa, vf, o[n]);
            }
        }
        __syncthreads();
    }

    // normalize + write [B*L][1024] bf16
    const int orow = qb0 + w * 16 + lk * 4;
    #pragma unroll
    for (int n = 0; n < 4; n++)
        #pragma unroll
        for (int r = 0; r < 4; r++) {
            float v = o[n][r] / l_r[r];
            out[((size_t)b * LSEQ + orow + r) * 1024 + h * 64 + n * 16 + lq] =
                f32_to_bf16(v);
        }
}

// ---------------- launch ----------------

extern "C" void kernel_launch(void* const* d_in, const int* in_sizes, int n_in,
                              void* d_out, int out_size, void* d_ws, size_t ws_size,
                              hipStream_t stream) {
    const float* x     = (const float*)d_in[0];
    const float* W_qkv = (const float*)d_in[1];
    const float* b_qkv = (const float*)d_in[2];
    const float* W_out = (const float*)d_in[3];
    const float* b_out = (const float*)d_in[4];
    float* out = (float*)d_out;

    char* p = (char*)d_ws;
    unsigned short* x_bf   = (unsigned short*)p; p += (size_t)NROWS * D_MODEL * 2;
    unsigned short* wqkv_t = (unsigned short*)p; p += (size_t)3 * D_MODEL * D_MODEL * 2;
    unsigned short* wout_t = (unsigned short*)p; p += (size_t)D_MODEL * D_MODEL * 2;
    unsigned short* qkv    = (unsigned short*)p; p += (size_t)NROWS * 3 * D_MODEL * 2;
    unsigned short* attn   = (unsigned short*)p;

    int n4 = NROWS * D_MODEL / 4;
    hipLaunchKernelGGL(cvt_f32_bf16, dim3((n4 + 255) / 256), dim3(256), 0, stream,
                       x, x_bf, n4);
    hipLaunchKernelGGL(transpose_cvt, dim3(3 * D_MODEL / 32, D_MODEL / 32), dim3(256),
                       0, stream, W_qkv, wqkv_t, D_MODEL, 3 * D_MODEL);
    hipLaunchKernelGGL(transpose_cvt, dim3(D_MODEL / 32, D_MODEL / 32), dim3(256),
                       0, stream, W_out, wout_t, D_MODEL, D_MODEL);
    hipLaunchKernelGGL((gemm_bf16<true>), dim3(3 * D_MODEL / 128, NROWS / 128),
                       dim3(256), 0, stream, x_bf, wqkv_t, b_qkv, (void*)qkv,
                       NROWS, 3 * D_MODEL, D_MODEL);
    hipLaunchKernelGGL(attn_kernel, dim3(LSEQ / 64, BATCH * NH), dim3(256), 0, stream,
                       qkv, attn);
    hipLaunchKernelGGL((gemm_bf16<false>), dim3(D_MODEL / 128, NROWS / 128),
                       dim3(256), 0, stream, attn, wout_t, b_out, (void*)out,
                       NROWS, D_MODEL, D_MODEL);
}

// Round 3
// 373.366 us; speedup vs baseline: 1.4026x; 1.4026x over previous
//
#include <hip/hip_runtime.h>
#include <hip/hip_bf16.h>
#include <stdint.h>

#define D_MODEL 1024
#define NH 16
#define HD 64
#define LSEQ 2048
#define BATCH 4
#define NROWS (BATCH * LSEQ) /* 8192 */
#define SCALE_L2E 0.18033688011112042f /* 0.125 * log2(e) */

typedef __attribute__((ext_vector_type(8))) short s16x8;
typedef __attribute__((ext_vector_type(4))) float f32x4;
typedef __attribute__((ext_vector_type(4))) int   i32x4;

static __device__ __forceinline__ f32x4 mfma_bf16(s16x8 a, s16x8 b, f32x4 c) {
    return __builtin_amdgcn_mfma_f32_16x16x32_bf16(a, b, c, 0, 0, 0);
}

static __device__ __forceinline__ unsigned short f32_to_bf16(float f) {
    unsigned int u = __float_as_uint(f);
    u = (u + 0x7fffu + ((u >> 16) & 1u)) >> 16;
    return (unsigned short)u;
}

static __device__ __forceinline__ unsigned long long pack4(float a, float b,
                                                           float c, float d) {
    return (unsigned long long)f32_to_bf16(a) |
           ((unsigned long long)f32_to_bf16(b) << 16) |
           ((unsigned long long)f32_to_bf16(c) << 32) |
           ((unsigned long long)f32_to_bf16(d) << 48);
}

static __device__ __forceinline__ void gload16(const void* g, void* l) {
    __builtin_amdgcn_global_load_lds(
        (const __attribute__((address_space(1))) void*)g,
        (__attribute__((address_space(3))) void*)l, 16, 0, 0);
}

// ---------------- conversion kernels ----------------

__global__ void cvt_f32_bf16(const float* __restrict__ in,
                             unsigned short* __restrict__ out, int n4) {
    int i = blockIdx.x * blockDim.x + threadIdx.x;
    if (i < n4) {
        float4 v = ((const float4*)in)[i];
        ushort4 o;
        o.x = f32_to_bf16(v.x); o.y = f32_to_bf16(v.y);
        o.z = f32_to_bf16(v.z); o.w = f32_to_bf16(v.w);
        ((ushort4*)out)[i] = o;
    }
}

// in: [K][N] f32  ->  out: [N][K] bf16
__global__ __launch_bounds__(256) void transpose_cvt(
    const float* __restrict__ in, unsigned short* __restrict__ out, int K, int N) {
    __shared__ float tile[32][33];
    int n0 = blockIdx.x * 32, k0 = blockIdx.y * 32;
    int tx = threadIdx.x & 31, ty = threadIdx.x >> 5; // 32 x 8
    #pragma unroll
    for (int i = 0; i < 4; i++) {
        int k = ty + i * 8;
        tile[k][tx] = in[(size_t)(k0 + k) * N + (n0 + tx)];
    }
    __syncthreads();
    #pragma unroll
    for (int i = 0; i < 4; i++) {
        int n = ty + i * 8;
        out[(size_t)(n0 + n) * K + (k0 + tx)] = f32_to_bf16(tile[tx][n]);
    }
}

// ---------------- GEMM: C = A[M][K] * Bt[N][K]^T + bias ----------------
// 128x128 tile, BK=32, 256 threads = 4 waves (2x2), global_load_lds staging.
// MODE 0: plain f32 C.  MODE 1: qkv routing (q scaled->q_buf, k->k_buf,
//                                v transposed -> vT[b,h][d][kv]).

template <int MODE>
__global__ __launch_bounds__(256) void gemm_bf16(
    const unsigned short* __restrict__ A,   // [M][K] bf16
    const unsigned short* __restrict__ Bt,  // [N][K] bf16
    const float* __restrict__ bias,         // [N] f32
    float* __restrict__ C,
    unsigned short* __restrict__ q_buf, unsigned short* __restrict__ k_buf,
    unsigned short* __restrict__ vT,
    int M, int N, int K) {
    __shared__ __align__(16) unsigned short As[128][32];
    __shared__ __align__(16) unsigned short Bs[128][32];

    const int tid = threadIdx.x;
    const int m0 = blockIdx.y * 128;
    const int n0 = blockIdx.x * 128;
    const int lane = tid & 63, w4 = tid >> 6;
    const int wr = w4 >> 1, wc = w4 & 1;
    const int lq = lane & 15, lk = lane >> 4;
    const int srow = lane >> 2;        // 0..15
    const int sk = (lane & 3) * 8;     // element offset within 32-k

    f32x4 acc[4][4];
    #pragma unroll
    for (int m = 0; m < 4; m++)
        #pragma unroll
        for (int n = 0; n < 4; n++)
            #pragma unroll
            for (int r = 0; r < 4; r++) acc[m][n][r] = 0.f;

    for (int k0 = 0; k0 < K; k0 += 32) {
        const unsigned short* ap = A  + (size_t)(m0 + w4 * 16 + srow) * K + k0 + sk;
        const unsigned short* bp = Bt + (size_t)(n0 + w4 * 16 + srow) * K + k0 + sk;
        gload16(ap,                  &As[w4 * 16][0]);
        gload16(ap + (size_t)64 * K, &As[64 + w4 * 16][0]);
        gload16(bp,                  &Bs[w4 * 16][0]);
        gload16(bp + (size_t)64 * K, &Bs[64 + w4 * 16][0]);
        __syncthreads();
        s16x8 af[4], bf[4];
        #pragma unroll
        for (int m = 0; m < 4; m++)
            af[m] = *(const s16x8*)(&As[wr * 64 + m * 16 + lq][lk * 8]);
        #pragma unroll
        for (int n = 0; n < 4; n++)
            bf[n] = *(const s16x8*)(&Bs[wc * 64 + n * 16 + lq][lk * 8]);
        #pragma unroll
        for (int m = 0; m < 4; m++)
            #pragma unroll
            for (int n = 0; n < 4; n++)
                acc[m][n] = mfma_bf16(af[m], bf[n], acc[m][n]);
        __syncthreads();
    }

    if (MODE == 0) {
        #pragma unroll
        for (int m = 0; m < 4; m++) {
            int row = m0 + wr * 64 + m * 16 + lk * 4;
            #pragma unroll
            for (int n = 0; n < 4; n++) {
                int col = n0 + wc * 64 + n * 16 + lq;
                float bv = bias[col];
                #pragma unroll
                for (int r = 0; r < 4; r++)
                    C[(size_t)(row + r) * N + col] = acc[m][n][r] + bv;
            }
        }
    } else {
        if (n0 < 1024) {          // q: scale by 0.125*log2e
            #pragma unroll
            for (int m = 0; m < 4; m++) {
                int row = m0 + wr * 64 + m * 16 + lk * 4;
                #pragma unroll
                for (int n = 0; n < 4; n++) {
                    int col = n0 + wc * 64 + n * 16 + lq;
                    float bv = bias[col];
                    #pragma unroll
                    for (int r = 0; r < 4; r++)
                        q_buf[(size_t)(row + r) * 1024 + col] =
                            f32_to_bf16((acc[m][n][r] + bv) * SCALE_L2E);
                }
            }
        } else if (n0 < 2048) {   // k
            #pragma unroll
            for (int m = 0; m < 4; m++) {
                int row = m0 + wr * 64 + m * 16 + lk * 4;
                #pragma unroll
                for (int n = 0; n < 4; n++) {
                    int col = n0 + wc * 64 + n * 16 + lq;
                    float bv = bias[col];
                    #pragma unroll
                    for (int r = 0; r < 4; r++)
                        k_buf[(size_t)(row + r) * 1024 + (col - 1024)] =
                            f32_to_bf16(acc[m][n][r] + bv);
                }
            }
        } else {                  // v -> vT[b,h][d][kv], packed 4-row stores
            #pragma unroll
            for (int m = 0; m < 4; m++) {
                int row = m0 + wr * 64 + m * 16 + lk * 4;
                int bb = row >> 11, pos = row & 2047;
                #pragma unroll
                for (int n = 0; n < 4; n++) {
                    int col = n0 + wc * 64 + n * 16 + lq;
                    int dg = col - 2048;
                    float bv = bias[col];
                    unsigned long long pk =
                        pack4(acc[m][n][0] + bv, acc[m][n][1] + bv,
                              acc[m][n][2] + bv, acc[m][n][3] + bv);
                    *(unsigned long long*)(vT +
                        ((size_t)((bb * 16 + (dg >> 6)) * 64 + (dg & 63))) * 2048 + pos) = pk;
                }
            }
        }
    }
}

// ---------------- flash attention (swapped QK^T, 4 waves x 16 q-rows) ------
// grid: (L/64 reversed, B*H); LDS: Ks[64][64] + Vs(V^T)[64][64] + P[4][16][64]
// all XOR-swizzled (byte ^= (row&7)<<4).

__global__ __launch_bounds__(256) void attn_kernel(
    const unsigned short* __restrict__ q_buf,
    const unsigned short* __restrict__ k_buf,
    const unsigned short* __restrict__ vT,
    unsigned short* __restrict__ out) {
    __shared__ __align__(16) char lds[24576];
    char* Ks = lds;
    char* Vs = lds + 8192;

    const int bh = blockIdx.y;
    const int b = bh >> 4, h = bh & 15;
    const int qb0 = ((int)gridDim.x - 1 - (int)blockIdx.x) * 64;
    const int tid = threadIdx.x, lane = tid & 63, w = tid >> 6;
    const int lq = lane & 15, lk = lane >> 4;
    char* Pw = lds + 16384 + w * 2048;

    const int q_g = qb0 + w * 16 + lq;   // this lane's q row (local to b)
    const unsigned short* qp = q_buf + ((size_t)b * LSEQ + q_g) * 1024 + h * 64;
    const s16x8 qf0 = *(const s16x8*)(qp + lk * 8);
    const s16x8 qf1 = *(const s16x8*)(qp + 32 + lk * 8);

    const unsigned short* kbase = k_buf + (size_t)b * LSEQ * 1024 + h * 64;
    const unsigned short* vbase = vT + (size_t)bh * 64 * 2048;

    const int srow = tid >> 3, sch = tid & 7;    // staging rows 0..31, chunk 0..7
    const int sby0 = (srow * 128 + sch * 16) ^ ((srow & 7) << 4);
    const int sby1 = ((srow + 32) * 128 + sch * 16) ^ ((srow & 7) << 4);
    const int swzA = (lq & 7) << 4;

    float m_r = -1e30f, l_r = 0.f;
    f32x4 o[4];
    #pragma unroll
    for (int n = 0; n < 4; n++)
        #pragma unroll
        for (int r = 0; r < 4; r++) o[n][r] = 0.f;

    const int nkv = qb0 / 64 + 1;

    i32x4 r0, r1, r2, r3;
    {
        const unsigned short* kp = kbase + (size_t)srow * 1024 + sch * 8;
        r0 = *(const i32x4*)kp;
        r1 = *(const i32x4*)(kp + (size_t)32 * 1024);
        const unsigned short* vp = vbase + (size_t)srow * 2048 + sch * 8;
        r2 = *(const i32x4*)vp;
        r3 = *(const i32x4*)(vp + (size_t)32 * 2048);
    }

    for (int kvb = 0; kvb < nkv; kvb++) {
        *(i32x4*)(Ks + sby0) = r0;
        *(i32x4*)(Ks + sby1) = r1;
        *(i32x4*)(Vs + sby0) = r2;
        *(i32x4*)(Vs + sby1) = r3;
        __syncthreads();
        if (kvb + 1 < nkv) {   // T14: prefetch next tile, hide under compute
            int kv0 = (kvb + 1) * 64;
            const unsigned short* kp = kbase + (size_t)(kv0 + srow) * 1024 + sch * 8;
            r0 = *(const i32x4*)kp;
            r1 = *(const i32x4*)(kp + (size_t)32 * 1024);
            const unsigned short* vp = vbase + (size_t)srow * 2048 + kv0 + sch * 8;
            r2 = *(const i32x4*)vp;
            r3 = *(const i32x4*)(vp + (size_t)32 * 2048);
        }

        // S^T = K Q^T : lane holds kv = n*16+lk*4+r, q = lq
        f32x4 sT[4];
        #pragma unroll
        for (int n = 0; n < 4; n++)
            #pragma unroll
            for (int r = 0; r < 4; r++) sT[n][r] = 0.f;
        #pragma unroll
        for (int n = 0; n < 4; n++) {
            const int rb = (n * 16 + lq) * 128;
            s16x8 a0 = *(const s16x8*)(Ks + ((rb + lk * 16) ^ swzA));
            s16x8 a1 = *(const s16x8*)(Ks + ((rb + 64 + lk * 16) ^ swzA));
            sT[n] = mfma_bf16(a0, qf0, sT[n]);
            sT[n] = mfma_bf16(a1, qf1, sT[n]);
        }
        if (kvb == nkv - 1) {  // only the diagonal tile needs masking
            const int kv0 = kvb * 64;
            #pragma unroll
            for (int n = 0; n < 4; n++)
                #pragma unroll
                for (int r = 0; r < 4; r++)
                    if (kv0 + n * 16 + lk * 4 + r > q_g) sT[n][r] = -1e30f;
        }

        // online softmax in exp2 domain (q pre-scaled by 0.125*log2e)
        float mx = -1e30f;
        #pragma unroll
        for (int n = 0; n < 4; n++)
            #pragma unroll
            for (int r = 0; r < 4; r++) mx = fmaxf(mx, sT[n][r]);
        mx = fmaxf(mx, __shfl_xor(mx, 16, 64));
        mx = fmaxf(mx, __shfl_xor(mx, 32, 64));
        const float mnew = fmaxf(m_r, mx);
        const float corr = exp2f(m_r - mnew);
        m_r = mnew;
        float sum = 0.f;
        unsigned long long pk[4];
        #pragma unroll
        for (int n = 0; n < 4; n++) {
            float p0 = exp2f(sT[n][0] - mnew);
            float p1 = exp2f(sT[n][1] - mnew);
            float p2 = exp2f(sT[n][2] - mnew);
            float p3 = exp2f(sT[n][3] - mnew);
            sum += (p0 + p1) + (p2 + p3);
            pk[n] = pack4(p0, p1, p2, p3);
        }
        sum += __shfl_xor(sum, 16, 64);
        sum += __shfl_xor(sum, 32, 64);
        l_r = l_r * corr + sum;
        #pragma unroll
        for (int n = 0; n < 4; n++)
            #pragma unroll
            for (int r = 0; r < 4; r++) o[n][r] *= corr;

        // P (bf16, packed b64 writes) -> wave-private LDS
        #pragma unroll
        for (int n = 0; n < 4; n++)
            *(unsigned long long*)(Pw + ((lq * 128 + n * 32 + lk * 8) ^ swzA)) = pk[n];
        asm volatile("s_waitcnt lgkmcnt(0)" ::: "memory");

        // O^T += V^T P^T : o[n] cols q=lq, rows d=n*16+lk*4+r
        #pragma unroll
        for (int kk = 0; kk < 2; kk++) {
            s16x8 pb = *(const s16x8*)(Pw + ((lq * 128 + kk * 64 + lk * 16) ^ swzA));
            #pragma unroll
            for (int n = 0; n < 4; n++) {
                s16x8 vf = *(const s16x8*)(Vs +
                    (((n * 16 + lq) * 128 + kk * 64 + lk * 16) ^ swzA));
                o[n] = mfma_bf16(vf, pb, o[n]);
            }
        }
        __syncthreads();
    }

    const float inv = 1.f / l_r;
    unsigned short* op = out + ((size_t)b * LSEQ + q_g) * 1024 + h * 64;
    #pragma unroll
    for (int n = 0; n < 4; n++) {
        unsigned long long pkv = pack4(o[n][0] * inv, o[n][1] * inv,
                                       o[n][2] * inv, o[n][3] * inv);
        *(unsigned long long*)(op + n * 16 + lk * 4) = pkv;
    }
}

// ---------------- launch ----------------

extern "C" void kernel_launch(void* const* d_in, const int* in_sizes, int n_in,
                              void* d_out, int out_size, void* d_ws, size_t ws_size,
                              hipStream_t stream) {
    const float* x     = (const float*)d_in[0];
    const float* W_qkv = (const float*)d_in[1];
    const float* b_qkv = (const float*)d_in[2];
    const float* W_out = (const float*)d_in[3];
    const float* b_out = (const float*)d_in[4];
    float* out = (float*)d_out;

    char* p = (char*)d_ws;
    unsigned short* x_bf   = (unsigned short*)p; p += (size_t)NROWS * D_MODEL * 2;
    unsigned short* wqkv_t = (unsigned short*)p; p += (size_t)3 * D_MODEL * D_MODEL * 2;
    unsigned short* wout_t = (unsigned short*)p; p += (size_t)D_MODEL * D_MODEL * 2;
    unsigned short* q_buf  = (unsigned short*)p; p += (size_t)NROWS * D_MODEL * 2;
    unsigned short* k_buf  = (unsigned short*)p; p += (size_t)NROWS * D_MODEL * 2;
    unsigned short* vT     = (unsigned short*)p; p += (size_t)NROWS * D_MODEL * 2;
    unsigned short* attn   = (unsigned short*)p;

    int n4 = NROWS * D_MODEL / 4;
    hipLaunchKernelGGL(cvt_f32_bf16, dim3((n4 + 255) / 256), dim3(256), 0, stream,
                       x, x_bf, n4);
    hipLaunchKernelGGL(transpose_cvt, dim3(3 * D_MODEL / 32, D_MODEL / 32), dim3(256),
                       0, stream, W_qkv, wqkv_t, D_MODEL, 3 * D_MODEL);
    hipLaunchKernelGGL(transpose_cvt, dim3(D_MODEL / 32, D_MODEL / 32), dim3(256),
                       0, stream, W_out, wout_t, D_MODEL, D_MODEL);
    hipLaunchKernelGGL((gemm_bf16<1>), dim3(3 * D_MODEL / 128, NROWS / 128),
                       dim3(256), 0, stream, x_bf, wqkv_t, b_qkv, (float*)nullptr,
                       q_buf, k_buf, vT, NROWS, 3 * D_MODEL, D_MODEL);
    hipLaunchKernelGGL(attn_kernel, dim3(LSEQ / 64, BATCH * NH), dim3(256), 0, stream,
                       q_buf, k_buf, vT, attn);
    hipLaunchKernelGGL((gemm_bf16<0>), dim3(D_MODEL / 128, NROWS / 128),
                       dim3(256), 0, stream, attn, wout_t, b_out, out,
                       (unsigned short*)nullptr, (unsigned short*)nullptr,
                       (unsigned short*)nullptr, NROWS, D_MODEL, D_MODEL);
}

// Round 4
// 331.633 us; speedup vs baseline: 1.5791x; 1.1258x over previous
//
#include <hip/hip_runtime.h>
#include <hip/hip_bf16.h>
#include <stdint.h>

#define D_MODEL 1024
#define NH 16
#define HD 64
#define LSEQ 2048
#define BATCH 4
#define NROWS (BATCH * LSEQ) /* 8192 */
#define SCALE_L2E 0.18033688011112042f /* 0.125 * log2(e) */

typedef __attribute__((ext_vector_type(8))) short s16x8;
typedef __attribute__((ext_vector_type(4))) float f32x4;
typedef __attribute__((ext_vector_type(4))) int   i32x4;

static __device__ __forceinline__ f32x4 mfma_bf16(s16x8 a, s16x8 b, f32x4 c) {
    return __builtin_amdgcn_mfma_f32_16x16x32_bf16(a, b, c, 0, 0, 0);
}

static __device__ __forceinline__ unsigned short f32_to_bf16(float f) {
    unsigned int u = __float_as_uint(f);
    u = (u + 0x7fffu + ((u >> 16) & 1u)) >> 16;
    return (unsigned short)u;
}

// packed f32x2 -> bf16x2 (T12 recipe; lo -> bits[15:0], hi -> bits[31:16])
static __device__ __forceinline__ unsigned int cvtpk(float lo, float hi) {
    unsigned int r;
    asm("v_cvt_pk_bf16_f32 %0, %1, %2" : "=v"(r) : "v"(lo), "v"(hi));
    return r;
}

static __device__ __forceinline__ unsigned long long pack4(float a, float b,
                                                           float c, float d) {
    return (unsigned long long)cvtpk(a, b) |
           ((unsigned long long)cvtpk(c, d) << 32);
}

static __device__ __forceinline__ void gload16(const void* g, void* l) {
    __builtin_amdgcn_global_load_lds(
        (const __attribute__((address_space(1))) void*)g,
        (__attribute__((address_space(3))) void*)l, 16, 0, 0);
}

// ---------------- conversion kernels ----------------

__global__ void cvt_f32_bf16(const float* __restrict__ in,
                             unsigned short* __restrict__ out, int n4) {
    int i = blockIdx.x * blockDim.x + threadIdx.x;
    if (i < n4) {
        float4 v = ((const float4*)in)[i];
        ushort4 o;
        o.x = f32_to_bf16(v.x); o.y = f32_to_bf16(v.y);
        o.z = f32_to_bf16(v.z); o.w = f32_to_bf16(v.w);
        ((ushort4*)out)[i] = o;
    }
}

// in: [K][N] f32  ->  out: [N][K] bf16
__global__ __launch_bounds__(256) void transpose_cvt(
    const float* __restrict__ in, unsigned short* __restrict__ out, int K, int N) {
    __shared__ float tile[32][33];
    int n0 = blockIdx.x * 32, k0 = blockIdx.y * 32;
    int tx = threadIdx.x & 31, ty = threadIdx.x >> 5; // 32 x 8
    #pragma unroll
    for (int i = 0; i < 4; i++) {
        int k = ty + i * 8;
        tile[k][tx] = in[(size_t)(k0 + k) * N + (n0 + tx)];
    }
    __syncthreads();
    #pragma unroll
    for (int i = 0; i < 4; i++) {
        int n = ty + i * 8;
        out[(size_t)(n0 + n) * K + (k0 + tx)] = f32_to_bf16(tile[tx][n]);
    }
}

// ---------------- GEMM: C = A[M][K] * Bt[N][K]^T + bias ----------------
// 128x128 tile, BK=32, 256 threads = 4 waves (2x2). T3 minimum-2-phase:
// double-buffered LDS, stage(next) issued BEFORE compute(cur), one barrier/step.
// MODE 0: plain f32 C.  MODE 1: qkv routing (q scaled->q_buf, k->k_buf,
//                                v transposed -> vT[b,h][d][kv]).

template <int MODE>
__global__ __launch_bounds__(256) void gemm_bf16(
    const unsigned short* __restrict__ A,   // [M][K] bf16
    const unsigned short* __restrict__ Bt,  // [N][K] bf16
    const float* __restrict__ bias,         // [N] f32
    float* __restrict__ C,
    unsigned short* __restrict__ q_buf, unsigned short* __restrict__ k_buf,
    unsigned short* __restrict__ vT,
    int M, int N, int K) {
    __shared__ __align__(16) unsigned short As[2][128][32];
    __shared__ __align__(16) unsigned short Bs[2][128][32];

    const int tid = threadIdx.x;
    const int m0 = blockIdx.y * 128;
    const int n0 = blockIdx.x * 128;
    const int lane = tid & 63, w4 = tid >> 6;
    const int wr = w4 >> 1, wc = w4 & 1;
    const int lq = lane & 15, lk = lane >> 4;
    const int srow = lane >> 2;        // 0..15
    const int sk = (lane & 3) * 8;     // element offset within 32-k

    const unsigned short* ap = A  + (size_t)(m0 + w4 * 16 + srow) * K + sk;
    const unsigned short* bp = Bt + (size_t)(n0 + w4 * 16 + srow) * K + sk;

    f32x4 acc[4][4];
    #pragma unroll
    for (int m = 0; m < 4; m++)
        #pragma unroll
        for (int n = 0; n < 4; n++)
            #pragma unroll
            for (int r = 0; r < 4; r++) acc[m][n][r] = 0.f;

    // prologue: stage K-step 0 into buf 0
    gload16(ap,                  &As[0][w4 * 16][0]);
    gload16(ap + (size_t)64 * K, &As[0][64 + w4 * 16][0]);
    gload16(bp,                  &Bs[0][w4 * 16][0]);
    gload16(bp + (size_t)64 * K, &Bs[0][64 + w4 * 16][0]);
    __syncthreads();

    int buf = 0;
    for (int k0 = 0; k0 < K; k0 += 32) {
        if (k0 + 32 < K) {   // issue next-tile stage BEFORE compute
            const unsigned short* ap2 = ap + k0 + 32;
            const unsigned short* bp2 = bp + k0 + 32;
            gload16(ap2,                  &As[buf ^ 1][w4 * 16][0]);
            gload16(ap2 + (size_t)64 * K, &As[buf ^ 1][64 + w4 * 16][0]);
            gload16(bp2,                  &Bs[buf ^ 1][w4 * 16][0]);
            gload16(bp2 + (size_t)64 * K, &Bs[buf ^ 1][64 + w4 * 16][0]);
        }
        s16x8 af[4], bfr[4];
        #pragma unroll
        for (int m = 0; m < 4; m++)
            af[m] = *(const s16x8*)(&As[buf][wr * 64 + m * 16 + lq][lk * 8]);
        #pragma unroll
        for (int n = 0; n < 4; n++)
            bfr[n] = *(const s16x8*)(&Bs[buf][wc * 64 + n * 16 + lq][lk * 8]);
        #pragma unroll
        for (int m = 0; m < 4; m++)
            #pragma unroll
            for (int n = 0; n < 4; n++)
                acc[m][n] = mfma_bf16(af[m], bfr[n], acc[m][n]);
        __syncthreads();   // drains vmcnt(0): staged tile ready; buf safe to reuse
        buf ^= 1;
    }

    if (MODE == 0) {
        #pragma unroll
        for (int m = 0; m < 4; m++) {
            int row = m0 + wr * 64 + m * 16 + lk * 4;
            #pragma unroll
            for (int n = 0; n < 4; n++) {
                int col = n0 + wc * 64 + n * 16 + lq;
                float bv = bias[col];
                #pragma unroll
                for (int r = 0; r < 4; r++)
                    C[(size_t)(row + r) * N + col] = acc[m][n][r] + bv;
            }
        }
    } else {
        if (n0 < 1024) {          // q: scale by 0.125*log2e
            #pragma unroll
            for (int m = 0; m < 4; m++) {
                int row = m0 + wr * 64 + m * 16 + lk * 4;
                #pragma unroll
                for (int n = 0; n < 4; n++) {
                    int col = n0 + wc * 64 + n * 16 + lq;
                    float bv = bias[col];
                    #pragma unroll
                    for (int r = 0; r < 4; r++)
                        q_buf[(size_t)(row + r) * 1024 + col] =
                            f32_to_bf16((acc[m][n][r] + bv) * SCALE_L2E);
                }
            }
        } else if (n0 < 2048) {   // k
            #pragma unroll
            for (int m = 0; m < 4; m++) {
                int row = m0 + wr * 64 + m * 16 + lk * 4;
                #pragma unroll
                for (int n = 0; n < 4; n++) {
                    int col = n0 + wc * 64 + n * 16 + lq;
                    float bv = bias[col];
                    #pragma unroll
                    for (int r = 0; r < 4; r++)
                        k_buf[(size_t)(row + r) * 1024 + (col - 1024)] =
                            f32_to_bf16(acc[m][n][r] + bv);
                }
            }
        } else {                  // v -> vT[b,h][d][kv], packed 4-row stores
            #pragma unroll
            for (int m = 0; m < 4; m++) {
                int row = m0 + wr * 64 + m * 16 + lk * 4;
                int bb = row >> 11, pos = row & 2047;
                #pragma unroll
                for (int n = 0; n < 4; n++) {
                    int col = n0 + wc * 64 + n * 16 + lq;
                    int dg = col - 2048;
                    float bv = bias[col];
                    unsigned long long pk =
                        pack4(acc[m][n][0] + bv, acc[m][n][1] + bv,
                              acc[m][n][2] + bv, acc[m][n][3] + bv);
                    *(unsigned long long*)(vT +
                        ((size_t)((bb * 16 + (dg >> 6)) * 64 + (dg & 63))) * 2048 + pos) = pk;
                }
            }
        }
    }
}

// ---------------- flash attention (swapped QK^T, 4 waves x 16 q-rows) ------
// grid: (L/64 reversed, B*H); LDS: Ks[64][64] + Vs(V^T)[64][64] + P[4][16][64]
// all XOR-swizzled (byte ^= (row&7)<<4). T13 defer-max, T12 cvt_pk, T5 setprio.

__global__ __launch_bounds__(256) void attn_kernel(
    const unsigned short* __restrict__ q_buf,
    const unsigned short* __restrict__ k_buf,
    const unsigned short* __restrict__ vT,
    unsigned short* __restrict__ out) {
    __shared__ __align__(16) char lds[24576];
    char* Ks = lds;
    char* Vs = lds + 8192;

    const int bh = blockIdx.y;
    const int b = bh >> 4, h = bh & 15;
    const int qb0 = ((int)gridDim.x - 1 - (int)blockIdx.x) * 64;
    const int tid = threadIdx.x, lane = tid & 63, w = tid >> 6;
    const int lq = lane & 15, lk = lane >> 4;
    char* Pw = lds + 16384 + w * 2048;

    const int q_g = qb0 + w * 16 + lq;   // this lane's q row (local to b)
    const unsigned short* qp = q_buf + ((size_t)b * LSEQ + q_g) * 1024 + h * 64;
    const s16x8 qf0 = *(const s16x8*)(qp + lk * 8);
    const s16x8 qf1 = *(const s16x8*)(qp + 32 + lk * 8);

    const int srow = tid >> 3, sch = tid & 7;    // staging rows 0..31, chunk 0..7
    const int sby0 = (srow * 128 + sch * 16) ^ ((srow & 7) << 4);
    const int sby1 = ((srow + 32) * 128 + sch * 16) ^ ((srow & 7) << 4);
    const int swzA = (lq & 7) << 4;

    const unsigned short* kp =
        k_buf + (size_t)b * LSEQ * 1024 + h * 64 + (size_t)srow * 1024 + sch * 8;
    const unsigned short* vp =
        vT + (size_t)bh * 64 * 2048 + (size_t)srow * 2048 + sch * 8;

    float m_r = -1e30f, l_r = 0.f;
    f32x4 o[4];
    #pragma unroll
    for (int n = 0; n < 4; n++)
        #pragma unroll
        for (int r = 0; r < 4; r++) o[n][r] = 0.f;

    const int nkv = qb0 / 64 + 1;

    i32x4 r0 = *(const i32x4*)kp;
    i32x4 r1 = *(const i32x4*)(kp + (size_t)32 * 1024);
    i32x4 r2 = *(const i32x4*)vp;
    i32x4 r3 = *(const i32x4*)(vp + (size_t)32 * 2048);

    for (int kvb = 0; kvb < nkv; kvb++) {
        *(i32x4*)(Ks + sby0) = r0;
        *(i32x4*)(Ks + sby1) = r1;
        *(i32x4*)(Vs + sby0) = r2;
        *(i32x4*)(Vs + sby1) = r3;
        __syncthreads();
        if (kvb + 1 < nkv) {   // T14: prefetch next tile, hide under compute
            kp += 64 * 1024;
            vp += 64;
            r0 = *(const i32x4*)kp;
            r1 = *(const i32x4*)(kp + (size_t)32 * 1024);
            r2 = *(const i32x4*)vp;
            r3 = *(const i32x4*)(vp + (size_t)32 * 2048);
        }

        // S^T = K Q^T : lane holds kv = n*16+lk*4+r, q = lq
        f32x4 sT[4];
        #pragma unroll
        for (int n = 0; n < 4; n++)
            #pragma unroll
            for (int r = 0; r < 4; r++) sT[n][r] = 0.f;
        __builtin_amdgcn_s_setprio(1);
        #pragma unroll
        for (int n = 0; n < 4; n++) {
            const int rb = (n * 16 + lq) * 128;
            s16x8 a0 = *(const s16x8*)(Ks + ((rb + lk * 16) ^ swzA));
            s16x8 a1 = *(const s16x8*)(Ks + ((rb + 64 + lk * 16) ^ swzA));
            sT[n] = mfma_bf16(a0, qf0, sT[n]);
            sT[n] = mfma_bf16(a1, qf1, sT[n]);
        }
        __builtin_amdgcn_s_setprio(0);
        if (kvb == nkv - 1) {  // only the diagonal tile needs masking
            const int kv0 = kvb * 64;
            #pragma unroll
            for (int n = 0; n < 4; n++)
                #pragma unroll
                for (int r = 0; r < 4; r++)
                    if (kv0 + n * 16 + lk * 4 + r > q_g) sT[n][r] = -1e30f;
        }

        // online softmax in exp2 domain (q pre-scaled by 0.125*log2e)
        float mx = sT[0][0];
        #pragma unroll
        for (int n = 0; n < 4; n++)
            #pragma unroll
            for (int r = 0; r < 4; r++) mx = fmaxf(mx, sT[n][r]);
        mx = fmaxf(mx, __shfl_xor(mx, 16, 64));
        mx = fmaxf(mx, __shfl_xor(mx, 32, 64));
        // T13 defer-max: only rescale when some row's max grew past threshold
        if (!__all(mx <= m_r + 8.f)) {
            const float mnew = fmaxf(m_r, mx);
            const float corr = __builtin_amdgcn_exp2f(m_r - mnew);
            m_r = mnew;
            l_r *= corr;
            #pragma unroll
            for (int n = 0; n < 4; n++)
                #pragma unroll
                for (int r = 0; r < 4; r++) o[n][r] *= corr;
        }
        float sum = 0.f;
        unsigned long long pk[4];
        #pragma unroll
        for (int n = 0; n < 4; n++) {
            float p0 = __builtin_amdgcn_exp2f(sT[n][0] - m_r);
            float p1 = __builtin_amdgcn_exp2f(sT[n][1] - m_r);
            float p2 = __builtin_amdgcn_exp2f(sT[n][2] - m_r);
            float p3 = __builtin_amdgcn_exp2f(sT[n][3] - m_r);
            sum += (p0 + p1) + (p2 + p3);
            pk[n] = pack4(p0, p1, p2, p3);
        }
        l_r += sum;   // per-lane partial; cross-lane reduce deferred to end

        // P (bf16, packed b64 writes) -> wave-private LDS
        #pragma unroll
        for (int n = 0; n < 4; n++)
            *(unsigned long long*)(Pw + ((lq * 128 + n * 32 + lk * 8) ^ swzA)) = pk[n];
        asm volatile("s_waitcnt lgkmcnt(0)" ::: "memory");

        // O^T += V^T P^T : o[n] cols q=lq, rows d=n*16+lk*4+r
        __builtin_amdgcn_s_setprio(1);
        #pragma unroll
        for (int kk = 0; kk < 2; kk++) {
            s16x8 pb = *(const s16x8*)(Pw + ((lq * 128 + kk * 64 + lk * 16) ^ swzA));
            #pragma unroll
            for (int n = 0; n < 4; n++) {
                s16x8 vf = *(const s16x8*)(Vs +
                    (((n * 16 + lq) * 128 + kk * 64 + lk * 16) ^ swzA));
                o[n] = mfma_bf16(vf, pb, o[n]);
            }
        }
        __builtin_amdgcn_s_setprio(0);
        __syncthreads();
    }

    l_r += __shfl_xor(l_r, 16, 64);
    l_r += __shfl_xor(l_r, 32, 64);
    const float inv = 1.f / l_r;
    unsigned short* op = out + ((size_t)b * LSEQ + q_g) * 1024 + h * 64;
    #pragma unroll
    for (int n = 0; n < 4; n++) {
        unsigned long long pkv = pack4(o[n][0] * inv, o[n][1] * inv,
                                       o[n][2] * inv, o[n][3] * inv);
        *(unsigned long long*)(op + n * 16 + lk * 4) = pkv;
    }
}

// ---------------- launch ----------------

extern "C" void kernel_launch(void* const* d_in, const int* in_sizes, int n_in,
                              void* d_out, int out_size, void* d_ws, size_t ws_size,
                              hipStream_t stream) {
    const float* x     = (const float*)d_in[0];
    const float* W_qkv = (const float*)d_in[1];
    const float* b_qkv = (const float*)d_in[2];
    const float* W_out = (const float*)d_in[3];
    const float* b_out = (const float*)d_in[4];
    float* out = (float*)d_out;

    char* p = (char*)d_ws;
    unsigned short* x_bf   = (unsigned short*)p; p += (size_t)NROWS * D_MODEL * 2;
    unsigned short* wqkv_t = (unsigned short*)p; p += (size_t)3 * D_MODEL * D_MODEL * 2;
    unsigned short* wout_t = (unsigned short*)p; p += (size_t)D_MODEL * D_MODEL * 2;
    unsigned short* q_buf  = (unsigned short*)p; p += (size_t)NROWS * D_MODEL * 2;
    unsigned short* k_buf  = (unsigned short*)p; p += (size_t)NROWS * D_MODEL * 2;
    unsigned short* vT     = (unsigned short*)p; p += (size_t)NROWS * D_MODEL * 2;
    unsigned short* attn   = (unsigned short*)p;

    int n4 = NROWS * D_MODEL / 4;
    hipLaunchKernelGGL(cvt_f32_bf16, dim3((n4 + 255) / 256), dim3(256), 0, stream,
                       x, x_bf, n4);
    hipLaunchKernelGGL(transpose_cvt, dim3(3 * D_MODEL / 32, D_MODEL / 32), dim3(256),
                       0, stream, W_qkv, wqkv_t, D_MODEL, 3 * D_MODEL);
    hipLaunchKernelGGL(transpose_cvt, dim3(D_MODEL / 32, D_MODEL / 32), dim3(256),
                       0, stream, W_out, wout_t, D_MODEL, D_MODEL);
    hipLaunchKernelGGL((gemm_bf16<1>), dim3(3 * D_MODEL / 128, NROWS / 128),
                       dim3(256), 0, stream, x_bf, wqkv_t, b_qkv, (float*)nullptr,
                       q_buf, k_buf, vT, NROWS, 3 * D_MODEL, D_MODEL);
    hipLaunchKernelGGL(attn_kernel, dim3(LSEQ / 64, BATCH * NH), dim3(256), 0, stream,
                       q_buf, k_buf, vT, attn);
    hipLaunchKernelGGL((gemm_bf16<0>), dim3(D_MODEL / 128, NROWS / 128),
                       dim3(256), 0, stream, attn, wout_t, b_out, out,
                       (unsigned short*)nullptr, (unsigned short*)nullptr,
                       (unsigned short*)nullptr, NROWS, D_MODEL, D_MODEL);
}

// Round 5
// 317.969 us; speedup vs baseline: 1.6469x; 1.0430x over previous
//
#include <hip/hip_runtime.h>
#include <hip/hip_bf16.h>
#include <stdint.h>

#define D_MODEL 1024
#define NH 16
#define HD 64
#define LSEQ 2048
#define BATCH 4
#define NROWS (BATCH * LSEQ) /* 8192 */
#define SCALE_L2E 0.18033688011112042f /* 0.125 * log2(e) */

typedef __attribute__((ext_vector_type(8))) short s16x8;
typedef __attribute__((ext_vector_type(4))) float f32x4;
typedef __attribute__((ext_vector_type(4))) int   i32x4;

static __device__ __forceinline__ f32x4 mfma_bf16(s16x8 a, s16x8 b, f32x4 c) {
    return __builtin_amdgcn_mfma_f32_16x16x32_bf16(a, b, c, 0, 0, 0);
}

static __device__ __forceinline__ unsigned short f32_to_bf16(float f) {
    unsigned int u = __float_as_uint(f);
    u = (u + 0x7fffu + ((u >> 16) & 1u)) >> 16;
    return (unsigned short)u;
}

// packed f32x2 -> bf16x2 (T12; lo -> bits[15:0], hi -> bits[31:16])
static __device__ __forceinline__ unsigned int cvtpk(float lo, float hi) {
    unsigned int r;
    asm("v_cvt_pk_bf16_f32 %0, %1, %2" : "=v"(r) : "v"(lo), "v"(hi));
    return r;
}

static __device__ __forceinline__ unsigned long long pack4(float a, float b,
                                                           float c, float d) {
    return (unsigned long long)cvtpk(a, b) |
           ((unsigned long long)cvtpk(c, d) << 32);
}

static __device__ __forceinline__ void gload16(const void* g, void* l) {
    __builtin_amdgcn_global_load_lds(
        (const __attribute__((address_space(1))) void*)g,
        (__attribute__((address_space(3))) void*)l, 16, 0, 0);
}

// ---------------- conversion kernels ----------------

__global__ void cvt_f32_bf16(const float* __restrict__ in,
                             unsigned short* __restrict__ out, int n4) {
    int i = blockIdx.x * blockDim.x + threadIdx.x;
    if (i < n4) {
        float4 v = ((const float4*)in)[i];
        ushort4 o;
        o.x = f32_to_bf16(v.x); o.y = f32_to_bf16(v.y);
        o.z = f32_to_bf16(v.z); o.w = f32_to_bf16(v.w);
        ((ushort4*)out)[i] = o;
    }
}

// in: [K][N] f32  ->  out: [N][K] bf16
__global__ __launch_bounds__(256) void transpose_cvt(
    const float* __restrict__ in, unsigned short* __restrict__ out, int K, int N) {
    __shared__ float tile[32][33];
    int n0 = blockIdx.x * 32, k0 = blockIdx.y * 32;
    int tx = threadIdx.x & 31, ty = threadIdx.x >> 5; // 32 x 8
    #pragma unroll
    for (int i = 0; i < 4; i++) {
        int k = ty + i * 8;
        tile[k][tx] = in[(size_t)(k0 + k) * N + (n0 + tx)];
    }
    __syncthreads();
    #pragma unroll
    for (int i = 0; i < 4; i++) {
        int n = ty + i * 8;
        out[(size_t)(n0 + n) * K + (k0 + tx)] = f32_to_bf16(tile[tx][n]);
    }
}

// ============ 256x256 8-phase QKV GEMM (T2+T3+T4+T5) ============
// qkv = x_bf[8192][1024] * wqkv_t[3072][1024]^T + b; routes q/k/vT.
// 8 waves (2M x 4N), BK=64, dbuf LDS 128KB, raw barriers + counted vmcnt(6).
// LDS half = [128 rows][64 k] bf16 linear; swizzle byte^=(row&7)<<4 applied
// via pre-swizzled GLOBAL source (gload_lds dest stays linear) + swizzled read.

__global__ __launch_bounds__(512, 2) void gemm256_qkv(
    const unsigned short* __restrict__ A,    // [8192][1024]
    const unsigned short* __restrict__ Bt,   // [3072][1024]
    const float* __restrict__ bias,          // [3072]
    unsigned short* __restrict__ q_buf, unsigned short* __restrict__ k_buf,
    unsigned short* __restrict__ vT) {
    extern __shared__ float4 smv[];
    char* sm = (char*)smv;
    const int K = 1024, NT = 16;
    const int tid = threadIdx.x;
    const int lane = tid & 63, w = tid >> 6;
    const int wm = w >> 2, wn = w & 3;
    const int lq = lane & 15, lk = lane >> 4;
    const int m0 = blockIdx.y * 256, n0 = blockIdx.x * 256;

    const unsigned short* GA = A + (size_t)m0 * K;
    const unsigned short* GB = Bt + (size_t)n0 * K;

    // stage one half-tile (128 rows x 64 k = 16KB): 2 gload16 per thread
    auto stage = [&](const unsigned short* G, int mat, int t, int half) {
        char* base = sm + (t & 1) * 65536 + mat * 32768 + half * 16384;
        const unsigned short* g0 = G + (size_t)(half * 128) * K + t * 64;
        #pragma unroll
        for (int j = 0; j < 2; j++) {
            int c = j * 512 + tid;
            int row = c >> 3, cc = c & 7;
            int cg = cc ^ (row & 7);                       // inverse swizzle on src
            gload16(g0 + (size_t)row * K + cg * 8,
                    base + (j * 512 + w * 64) * 16);        // wave-uniform dest
        }
    };
    auto lda = [&](int buf, int mf, int ks) -> s16x8 {
        int byte = (((mf * 16 + lq) * 128 + ks * 64 + lk * 16)) ^ ((lq & 7) << 4);
        return *(const s16x8*)(sm + buf * 65536 + wm * 16384 + byte);
    };
    auto ldb = [&](int buf, int nf, int ks) -> s16x8 {
        int byte = ((((wn & 1) * 64 + nf * 16 + lq) * 128 + ks * 64 + lk * 16)) ^
                   ((lq & 7) << 4);
        return *(const s16x8*)(sm + buf * 65536 + 32768 + (wn >> 1) * 16384 + byte);
    };

    f32x4 acc[8][4];
    #pragma unroll
    for (int m = 0; m < 8; m++)
        #pragma unroll
        for (int n = 0; n < 4; n++)
            #pragma unroll
            for (int r = 0; r < 4; r++) acc[m][n][r] = 0.f;

    // prologue: tile0 (4 halves) + tile1 first 3 halves; wait tile0 landed
    stage(GA, 0, 0, 0); stage(GA, 0, 0, 1); stage(GB, 1, 0, 0); stage(GB, 1, 0, 1);
    stage(GA, 0, 1, 0); stage(GA, 0, 1, 1); stage(GB, 1, 1, 0);
    asm volatile("s_waitcnt vmcnt(6)" ::: "memory");
    __builtin_amdgcn_s_barrier();

    s16x8 alo[4][2], ahi[4][2], blo[2][2], bhi[2][2];
    for (int t = 0; t < NT; t++) {
        const int buf = t & 1;
        // ---- P0: read A-lo + B-lo; stage B_{t+1} h1 (other buf, always safe)
        #pragma unroll
        for (int mf = 0; mf < 4; mf++)
            #pragma unroll
            for (int ks = 0; ks < 2; ks++) alo[mf][ks] = lda(buf, mf, ks);
        #pragma unroll
        for (int nf = 0; nf < 2; nf++)
            #pragma unroll
            for (int ks = 0; ks < 2; ks++) blo[nf][ks] = ldb(buf, nf, ks);
        if (t + 1 < NT) stage(GB, 1, t + 1, 1);
        __builtin_amdgcn_s_barrier();
        asm volatile("s_waitcnt lgkmcnt(0)" ::: "memory");
        __builtin_amdgcn_s_setprio(1);
        #pragma unroll
        for (int mf = 0; mf < 4; mf++)
            #pragma unroll
            for (int nf = 0; nf < 2; nf++)
                #pragma unroll
                for (int ks = 0; ks < 2; ks++)
                    acc[mf][nf] = mfma_bf16(alo[mf][ks], blo[nf][ks], acc[mf][nf]);
        __builtin_amdgcn_s_setprio(0);
        __builtin_amdgcn_s_barrier();
        // ---- P1: read B-hi
        #pragma unroll
        for (int nf = 0; nf < 2; nf++)
            #pragma unroll
            for (int ks = 0; ks < 2; ks++) bhi[nf][ks] = ldb(buf, 2 + nf, ks);
        __builtin_amdgcn_s_barrier();
        asm volatile("s_waitcnt lgkmcnt(0)" ::: "memory");
        __builtin_amdgcn_s_setprio(1);
        #pragma unroll
        for (int mf = 0; mf < 4; mf++)
            #pragma unroll
            for (int nf = 0; nf < 2; nf++)
                #pragma unroll
                for (int ks = 0; ks < 2; ks++)
                    acc[mf][2 + nf] = mfma_bf16(alo[mf][ks], bhi[nf][ks], acc[mf][2 + nf]);
        __builtin_amdgcn_s_setprio(0);
        __builtin_amdgcn_s_barrier();
        // ---- P2: read A-hi; stage B_{t+2} h0 (B halves dead after P1)
        #pragma unroll
        for (int mf = 0; mf < 4; mf++)
            #pragma unroll
            for (int ks = 0; ks < 2; ks++) ahi[mf][ks] = lda(buf, 4 + mf, ks);
        if (t + 2 < NT) stage(GB, 1, t + 2, 0);
        __builtin_amdgcn_s_barrier();
        asm volatile("s_waitcnt lgkmcnt(0)" ::: "memory");
        __builtin_amdgcn_s_setprio(1);
        #pragma unroll
        for (int mf = 0; mf < 4; mf++)
            #pragma unroll
            for (int nf = 0; nf < 2; nf++)
                #pragma unroll
                for (int ks = 0; ks < 2; ks++)
                    acc[4 + mf][nf] = mfma_bf16(ahi[mf][ks], blo[nf][ks], acc[4 + mf][nf]);
        __builtin_amdgcn_s_setprio(0);
        __builtin_amdgcn_s_barrier();
        // ---- P3: stage A_{t+2} h0+h1 (A halves dead after P2)
        if (t + 2 < NT) { stage(GA, 0, t + 2, 0); stage(GA, 0, t + 2, 1); }
        __builtin_amdgcn_s_barrier();
        asm volatile("s_waitcnt lgkmcnt(0)" ::: "memory");
        __builtin_amdgcn_s_setprio(1);
        #pragma unroll
        for (int mf = 0; mf < 4; mf++)
            #pragma unroll
            for (int nf = 0; nf < 2; nf++)
                #pragma unroll
                for (int ks = 0; ks < 2; ks++)
                    acc[4 + mf][2 + nf] = mfma_bf16(ahi[mf][ks], bhi[nf][ks], acc[4 + mf][2 + nf]);
        __builtin_amdgcn_s_setprio(0);
        // end-of-tile: counted wait — tile t+1 fully landed, 3 halves in flight
        if (t + 2 < NT) {
            asm volatile("s_waitcnt vmcnt(6)" ::: "memory");
        } else if (t + 1 < NT) {
            asm volatile("s_waitcnt vmcnt(0)" ::: "memory");
        }
        __builtin_amdgcn_s_barrier();
    }

    // epilogue: route q (scaled) / k / v->vT
    const int rowb = m0 + wm * 128 + lk * 4;
    const int colb = n0 + wn * 64 + lq;
    if (n0 < 1024) {
        #pragma unroll
        for (int mf = 0; mf < 8; mf++) {
            int row = rowb + mf * 16;
            #pragma unroll
            for (int nf = 0; nf < 4; nf++) {
                int col = colb + nf * 16;
                float bv = bias[col];
                #pragma unroll
                for (int r = 0; r < 4; r++)
                    q_buf[(size_t)(row + r) * 1024 + col] =
                        f32_to_bf16((acc[mf][nf][r] + bv) * SCALE_L2E);
            }
        }
    } else if (n0 < 2048) {
        #pragma unroll
        for (int mf = 0; mf < 8; mf++) {
            int row = rowb + mf * 16;
            #pragma unroll
            for (int nf = 0; nf < 4; nf++) {
                int col = colb + nf * 16;
                float bv = bias[col];
                #pragma unroll
                for (int r = 0; r < 4; r++)
                    k_buf[(size_t)(row + r) * 1024 + (col - 1024)] =
                        f32_to_bf16(acc[mf][nf][r] + bv);
            }
        }
    } else {
        #pragma unroll
        for (int mf = 0; mf < 8; mf++) {
            int row = rowb + mf * 16;
            int bb = row >> 11, pos = row & 2047;
            #pragma unroll
            for (int nf = 0; nf < 4; nf++) {
                int col = colb + nf * 16;
                int dg = col - 2048;
                float bv = bias[col];
                unsigned long long pk =
                    pack4(acc[mf][nf][0] + bv, acc[mf][nf][1] + bv,
                          acc[mf][nf][2] + bv, acc[mf][nf][3] + bv);
                *(unsigned long long*)(vT +
                    ((size_t)((bb * 16 + (dg >> 6)) * 64 + (dg & 63))) * 2048 + pos) = pk;
            }
        }
    }
}

// ---------------- GEMM (128x128) for out-proj ----------------

__global__ __launch_bounds__(256) void gemm_bf16_f32(
    const unsigned short* __restrict__ A,   // [M][K] bf16
    const unsigned short* __restrict__ Bt,  // [N][K] bf16
    const float* __restrict__ bias,         // [N] f32
    float* __restrict__ C, int M, int N, int K) {
    __shared__ __align__(16) unsigned short As[2][128][32];
    __shared__ __align__(16) unsigned short Bs[2][128][32];

    const int tid = threadIdx.x;
    const int m0 = blockIdx.y * 128;
    const int n0 = blockIdx.x * 128;
    const int lane = tid & 63, w4 = tid >> 6;
    const int wr = w4 >> 1, wc = w4 & 1;
    const int lq = lane & 15, lk = lane >> 4;

    const int srow = lane >> 2;
    const int sk = (lane & 3) * 8;
    const unsigned short* ap = A  + (size_t)(m0 + w4 * 16 + srow) * K + sk;
    const unsigned short* bp = Bt + (size_t)(n0 + w4 * 16 + srow) * K + sk;

    f32x4 acc[4][4];
    #pragma unroll
    for (int m = 0; m < 4; m++)
        #pragma unroll
        for (int n = 0; n < 4; n++)
            #pragma unroll
            for (int r = 0; r < 4; r++) acc[m][n][r] = 0.f;

    gload16(ap,                  &As[0][w4 * 16][0]);
    gload16(ap + (size_t)64 * K, &As[0][64 + w4 * 16][0]);
    gload16(bp,                  &Bs[0][w4 * 16][0]);
    gload16(bp + (size_t)64 * K, &Bs[0][64 + w4 * 16][0]);
    __syncthreads();

    int buf = 0;
    for (int k0 = 0; k0 < K; k0 += 32) {
        if (k0 + 32 < K) {
            const unsigned short* ap2 = ap + k0 + 32;
            const unsigned short* bp2 = bp + k0 + 32;
            gload16(ap2,                  &As[buf ^ 1][w4 * 16][0]);
            gload16(ap2 + (size_t)64 * K, &As[buf ^ 1][64 + w4 * 16][0]);
            gload16(bp2,                  &Bs[buf ^ 1][w4 * 16][0]);
            gload16(bp2 + (size_t)64 * K, &Bs[buf ^ 1][64 + w4 * 16][0]);
        }
        s16x8 af[4], bfr[4];
        #pragma unroll
        for (int m = 0; m < 4; m++)
            af[m] = *(const s16x8*)(&As[buf][wr * 64 + m * 16 + lq][lk * 8]);
        #pragma unroll
        for (int n = 0; n < 4; n++)
            bfr[n] = *(const s16x8*)(&Bs[buf][wc * 64 + n * 16 + lq][lk * 8]);
        #pragma unroll
        for (int m = 0; m < 4; m++)
            #pragma unroll
            for (int n = 0; n < 4; n++)
                acc[m][n] = mfma_bf16(af[m], bfr[n], acc[m][n]);
        __syncthreads();
        buf ^= 1;
    }

    #pragma unroll
    for (int m = 0; m < 4; m++) {
        int row = m0 + wr * 64 + m * 16 + lk * 4;
        #pragma unroll
        for (int n = 0; n < 4; n++) {
            int col = n0 + wc * 64 + n * 16 + lq;
            float bv = bias[col];
            #pragma unroll
            for (int r = 0; r < 4; r++)
                C[(size_t)(row + r) * N + col] = acc[m][n][r] + bv;
        }
    }
}

// ---------------- flash attention (swapped QK^T, 4 waves x 16 q-rows) ------

__global__ __launch_bounds__(256) void attn_kernel(
    const unsigned short* __restrict__ q_buf,
    const unsigned short* __restrict__ k_buf,
    const unsigned short* __restrict__ vT,
    unsigned short* __restrict__ out) {
    __shared__ __align__(16) char lds[24576];
    char* Ks = lds;
    char* Vs = lds + 8192;

    const int bh = blockIdx.y;
    const int b = bh >> 4, h = bh & 15;
    const int qb0 = ((int)gridDim.x - 1 - (int)blockIdx.x) * 64;
    const int tid = threadIdx.x, lane = tid & 63, w = tid >> 6;
    const int lq = lane & 15, lk = lane >> 4;
    char* Pw = lds + 16384 + w * 2048;

    const int q_g = qb0 + w * 16 + lq;
    const unsigned short* qp = q_buf + ((size_t)b * LSEQ + q_g) * 1024 + h * 64;
    const s16x8 qf0 = *(const s16x8*)(qp + lk * 8);
    const s16x8 qf1 = *(const s16x8*)(qp + 32 + lk * 8);

    const int srow = tid >> 3, sch = tid & 7;
    const int sby0 = (srow * 128 + sch * 16) ^ ((srow & 7) << 4);
    const int sby1 = ((srow + 32) * 128 + sch * 16) ^ ((srow & 7) << 4);
    const int swzA = (lq & 7) << 4;

    const unsigned short* kp =
        k_buf + (size_t)b * LSEQ * 1024 + h * 64 + (size_t)srow * 1024 + sch * 8;
    const unsigned short* vp =
        vT + (size_t)bh * 64 * 2048 + (size_t)srow * 2048 + sch * 8;

    float m_r = -1e30f, l_r = 0.f;
    f32x4 o[4];
    #pragma unroll
    for (int n = 0; n < 4; n++)
        #pragma unroll
        for (int r = 0; r < 4; r++) o[n][r] = 0.f;

    const int nkv = qb0 / 64 + 1;

    i32x4 r0 = *(const i32x4*)kp;
    i32x4 r1 = *(const i32x4*)(kp + (size_t)32 * 1024);
    i32x4 r2 = *(const i32x4*)vp;
    i32x4 r3 = *(const i32x4*)(vp + (size_t)32 * 2048);

    for (int kvb = 0; kvb < nkv; kvb++) {
        *(i32x4*)(Ks + sby0) = r0;
        *(i32x4*)(Ks + sby1) = r1;
        *(i32x4*)(Vs + sby0) = r2;
        *(i32x4*)(Vs + sby1) = r3;
        __syncthreads();
        if (kvb + 1 < nkv) {   // T14 prefetch: stays in flight across raw barrier
            kp += 64 * 1024;
            vp += 64;
            r0 = *(const i32x4*)kp;
            r1 = *(const i32x4*)(kp + (size_t)32 * 1024);
            r2 = *(const i32x4*)vp;
            r3 = *(const i32x4*)(vp + (size_t)32 * 2048);
        }

        f32x4 sT[4];
        #pragma unroll
        for (int n = 0; n < 4; n++)
            #pragma unroll
            for (int r = 0; r < 4; r++) sT[n][r] = 0.f;
        __builtin_amdgcn_s_setprio(1);
        #pragma unroll
        for (int n = 0; n < 4; n++) {
            const int rb = (n * 16 + lq) * 128;
            s16x8 a0 = *(const s16x8*)(Ks + ((rb + lk * 16) ^ swzA));
            s16x8 a1 = *(const s16x8*)(Ks + ((rb + 64 + lk * 16) ^ swzA));
            sT[n] = mfma_bf16(a0, qf0, sT[n]);
            sT[n] = mfma_bf16(a1, qf1, sT[n]);
        }
        __builtin_amdgcn_s_setprio(0);
        if (kvb == nkv - 1) {
            const int kv0 = kvb * 64;
            #pragma unroll
            for (int n = 0; n < 4; n++)
                #pragma unroll
                for (int r = 0; r < 4; r++)
                    if (kv0 + n * 16 + lk * 4 + r > q_g) sT[n][r] = -1e30f;
        }

        float mx = sT[0][0];
        #pragma unroll
        for (int n = 0; n < 4; n++)
            #pragma unroll
            for (int r = 0; r < 4; r++) mx = fmaxf(mx, sT[n][r]);
        mx = fmaxf(mx, __shfl_xor(mx, 16, 64));
        mx = fmaxf(mx, __shfl_xor(mx, 32, 64));
        if (!__all(mx <= m_r + 8.f)) {   // T13 defer-max
            const float mnew = fmaxf(m_r, mx);
            const float corr = __builtin_amdgcn_exp2f(m_r - mnew);
            m_r = mnew;
            l_r *= corr;
            #pragma unroll
            for (int n = 0; n < 4; n++)
                #pragma unroll
                for (int r = 0; r < 4; r++) o[n][r] *= corr;
        }
        float sum = 0.f;
        unsigned long long pk[4];
        #pragma unroll
        for (int n = 0; n < 4; n++) {
            float p0 = __builtin_amdgcn_exp2f(sT[n][0] - m_r);
            float p1 = __builtin_amdgcn_exp2f(sT[n][1] - m_r);
            float p2 = __builtin_amdgcn_exp2f(sT[n][2] - m_r);
            float p3 = __builtin_amdgcn_exp2f(sT[n][3] - m_r);
            sum += (p0 + p1) + (p2 + p3);
            pk[n] = pack4(p0, p1, p2, p3);
        }
        l_r += sum;

        #pragma unroll
        for (int n = 0; n < 4; n++)
            *(unsigned long long*)(Pw + ((lq * 128 + n * 32 + lk * 8) ^ swzA)) = pk[n];
        asm volatile("s_waitcnt lgkmcnt(0)" ::: "memory");

        __builtin_amdgcn_s_setprio(1);
        #pragma unroll
        for (int kk = 0; kk < 2; kk++) {
            s16x8 pb = *(const s16x8*)(Pw + ((lq * 128 + kk * 64 + lk * 16) ^ swzA));
            #pragma unroll
            for (int n = 0; n < 4; n++) {
                s16x8 vf = *(const s16x8*)(Vs +
                    (((n * 16 + lq) * 128 + kk * 64 + lk * 16) ^ swzA));
                o[n] = mfma_bf16(vf, pb, o[n]);
            }
        }
        __builtin_amdgcn_s_setprio(0);
        // raw barrier (no vmcnt drain): all LDS reads already consumed by MFMAs
        asm volatile("s_barrier" ::: "memory");
    }

    l_r += __shfl_xor(l_r, 16, 64);
    l_r += __shfl_xor(l_r, 32, 64);
    const float inv = 1.f / l_r;
    unsigned short* op = out + ((size_t)b * LSEQ + q_g) * 1024 + h * 64;
    #pragma unroll
    for (int n = 0; n < 4; n++) {
        unsigned long long pkv = pack4(o[n][0] * inv, o[n][1] * inv,
                                       o[n][2] * inv, o[n][3] * inv);
        *(unsigned long long*)(op + n * 16 + lk * 4) = pkv;
    }
}

// ---------------- launch ----------------

extern "C" void kernel_launch(void* const* d_in, const int* in_sizes, int n_in,
                              void* d_out, int out_size, void* d_ws, size_t ws_size,
                              hipStream_t stream) {
    const float* x     = (const float*)d_in[0];
    const float* W_qkv = (const float*)d_in[1];
    const float* b_qkv = (const float*)d_in[2];
    const float* W_out = (const float*)d_in[3];
    const float* b_out = (const float*)d_in[4];
    float* out = (float*)d_out;

    char* p = (char*)d_ws;
    unsigned short* x_bf   = (unsigned short*)p; p += (size_t)NROWS * D_MODEL * 2;
    unsigned short* wqkv_t = (unsigned short*)p; p += (size_t)3 * D_MODEL * D_MODEL * 2;
    unsigned short* wout_t = (unsigned short*)p; p += (size_t)D_MODEL * D_MODEL * 2;
    unsigned short* q_buf  = (unsigned short*)p; p += (size_t)NROWS * D_MODEL * 2;
    unsigned short* k_buf  = (unsigned short*)p; p += (size_t)NROWS * D_MODEL * 2;
    unsigned short* vT     = (unsigned short*)p; p += (size_t)NROWS * D_MODEL * 2;
    unsigned short* attn   = (unsigned short*)p;

    hipFuncSetAttribute((const void*)gemm256_qkv,
                        hipFuncAttributeMaxDynamicSharedMemorySize, 131072);

    int n4 = NROWS * D_MODEL / 4;
    hipLaunchKernelGGL(cvt_f32_bf16, dim3((n4 + 255) / 256), dim3(256), 0, stream,
                       x, x_bf, n4);
    hipLaunchKernelGGL(transpose_cvt, dim3(3 * D_MODEL / 32, D_MODEL / 32), dim3(256),
                       0, stream, W_qkv, wqkv_t, D_MODEL, 3 * D_MODEL);
    hipLaunchKernelGGL(transpose_cvt, dim3(D_MODEL / 32, D_MODEL / 32), dim3(256),
                       0, stream, W_out, wout_t, D_MODEL, D_MODEL);
    hipLaunchKernelGGL(gemm256_qkv, dim3(3 * D_MODEL / 256, NROWS / 256),
                       dim3(512), 131072, stream, x_bf, wqkv_t, b_qkv,
                       q_buf, k_buf, vT);
    hipLaunchKernelGGL(attn_kernel, dim3(LSEQ / 64, BATCH * NH), dim3(256), 0, stream,
                       q_buf, k_buf, vT, attn);
    hipLaunchKernelGGL(gemm_bf16_f32, dim3(D_MODEL / 128, NROWS / 128),
                       dim3(256), 0, stream, attn, wout_t, b_out, out,
                       NROWS, D_MODEL, D_MODEL);
}